// Round 3
// baseline (634.129 us; speedup 1.0000x reference)
//
#include <hip/hip_runtime.h>
#include <stdint.h>

// Viterbi CRF decode: B=1024, T=1024, N=34 (32 tags + START=32 + END=33)
// One wave per batch, one wave per 64-thread block (grid 1024 = 1 wave/SIMD).
// lane j = target state (j<34 active). Scores broadcast via per-block LDS;
// same-wave DS ops are in-order -> NO barriers in the forward recursion.
// launch_bounds(64,1) -> full VGPR budget so q/trans/candidates stay resident
// (round-2 failure: VGPR=64 forced LDS-read sinking onto the critical path).
#define BB 1024
#define TT 1024
#define NN 34
#define NEGV -6969.0f

typedef float v2f __attribute__((ext_vector_type(2)));
typedef float v4f __attribute__((ext_vector_type(4)));

__device__ __forceinline__ float fmax3(float a, float b, float c) {
    return fmaxf(fmaxf(a, b), c);   // fuses to v_max3_f32
}
__device__ __forceinline__ int imin2(int a, int b) { return a < b ? a : b; }
__device__ __forceinline__ int imin3(int a, int b, int c) {
    return imin2(imin2(a, b), c);   // fuses to v_min3_i32
}

__global__ __launch_bounds__(64, 1) void viterbi_wave(
        const float* __restrict__ feat,   // [B,T,34]
        const float* __restrict__ trans,  // [34,34]
        unsigned char* __restrict__ bpg,  // workspace [B,T,34] backpointers
        float* __restrict__ out)          // best[B] ++ path[B,T+1]
{
    __shared__ __align__(16) float scW[64];   // score broadcast (this wave only)
    __shared__ unsigned char Fm[16][NN];      // backtrack level-1 results
    __shared__ int Eb[16];                    // backtrack level-2 carries

    const int lane = threadIdx.x & 63;
    const int j    = lane;                    // target state
    const int jm   = (j < NN) ? j : (NN - 1); // clamp for idle lanes
    const bool act = (j < NN);
    const int bg   = blockIdx.x;

    // ---- per-lane constants: transitions row j (34 floats, packed)
    v4f t4[8]; v2f t2;
    {
        const float* trow = trans + jm * NN;
#pragma unroll
        for (int i = 0; i < 8; ++i)
            t4[i] = (v4f){trow[4*i], trow[4*i+1], trow[4*i+2], trow[4*i+3]};
        t2 = (v2f){trow[32], trow[33]};
    }

    const float* fp = feat + (size_t)bg * TT * NN + jm;
    unsigned char* bpt = bpg + (size_t)bg * TT * NN + j;

    const v4f* const S4 = (const v4f*)scW;
    const v2f* const S2 = (const v2f*)scW;

    // ---- init scores (lane k holds score[k]); lanes>=34 junk, never read
    scW[lane] = (lane == 32) ? 0.0f : NEGV;

    // first broadcast read (same-wave in-order DS after the write above)
    v4f q[8]; v2f q8;
#pragma unroll
    for (int i = 0; i < 8; ++i) q[i] = S4[i];
    q8 = S2[16];

    // 4-deep feature prefetch ring (t = 0..3)
    float fr0 = fp[0*NN], fr1 = fp[1*NN], fr2 = fp[2*NN], fr3 = fp[3*NN];

    // one Viterbi step. exact fp order (s+f)+tr; argmax = first index at max.
    // order: adds -> max tree -> publish m -> refill reads (pinned early by
    // sched_barrier) -> argmax eq-TREE + bp store run in the LDS shadow.
    auto vstep = [&](float fv, unsigned char* bpw) {
        const v4f f4 = (v4f){fv, fv, fv, fv};
        const v2f f2 = (v2f){fv, fv};
        v4f w[8]; v2f w8;
#pragma unroll
        for (int i = 0; i < 8; ++i) w[i] = (q[i] + f4) + t4[i];  // v_pk_add_f32
        w8 = (q8 + f2) + t2;
        float wv[NN];
#pragma unroll
        for (int i = 0; i < 8; ++i) {
            wv[4*i+0] = w[i].x; wv[4*i+1] = w[i].y;
            wv[4*i+2] = w[i].z; wv[4*i+3] = w[i].w;
        }
        wv[32] = w8.x; wv[33] = w8.y;
        float a[12];
#pragma unroll
        for (int i = 0; i < 11; ++i) a[i] = fmax3(wv[3*i], wv[3*i+1], wv[3*i+2]);
        a[11] = wv[33];
        float b0 = fmax3(a[0], a[1], a[2]), b1 = fmax3(a[3], a[4], a[5]);
        float b2 = fmax3(a[6], a[7], a[8]), b3 = fmax3(a[9], a[10], a[11]);
        float m = fmaxf(fmaxf(b0, b1), fmaxf(b2, b3));
        scW[lane] = m;                       // publish score[j] for next step
#pragma unroll
        for (int i = 0; i < 8; ++i) q[i] = S4[i];   // refill (in-order RAW)
        q8 = S2[16];
        __builtin_amdgcn_sched_barrier(0);   // loads stay ABOVE the scan
        // argmax: independent eq ops + min3 tree (no serial VCC/am chain)
        int e[NN];
#pragma unroll
        for (int k = 0; k < NN; ++k) e[k] = (wv[k] == m) ? k : 127;
        int r[12];
#pragma unroll
        for (int i = 0; i < 11; ++i) r[i] = imin3(e[3*i], e[3*i+1], e[3*i+2]);
        r[11] = e[33];
        int s0 = imin3(r[0], r[1], r[2]),  s1 = imin3(r[3], r[4], r[5]);
        int s2 = imin3(r[6], r[7], r[8]),  s3 = imin3(r[9], r[10], r[11]);
        int am = imin2(imin2(s0, s1), imin2(s2, s3));
        if (act) *bpw = (unsigned char)am;
    };

    // ---- forward: 255 iters x 4 steps (prefetch t+4) + 4-step epilogue
    for (int n = 0; n < 255; ++n) {
        { float f = fr0; fr0 = fp[4*NN]; vstep(f, bpt + 0*NN); }
        { float f = fr1; fr1 = fp[5*NN]; vstep(f, bpt + 1*NN); }
        { float f = fr2; fr2 = fp[6*NN]; vstep(f, bpt + 2*NN); }
        { float f = fr3; fr3 = fp[7*NN]; vstep(f, bpt + 3*NN); }
        fp += 4*NN; bpt += 4*NN;
    }
    vstep(fr0, bpt + 0*NN);
    vstep(fr1, bpt + 1*NN);
    vstep(fr2, bpt + 2*NN);
    vstep(fr3, bpt + 3*NN);
    // q now holds the broadcast of final scores (t=1024) in every lane.

    // ---- end transition + final argmax (redundant in all lanes, no LDS)
    int bi;
    float bm;
    {
        const float* er = trans + (NN - 1) * NN;   // uniform -> s_loads
        float wv[NN];
        float qv[NN];
#pragma unroll
        for (int i = 0; i < 8; ++i) {
            qv[4*i+0] = q[i].x; qv[4*i+1] = q[i].y;
            qv[4*i+2] = q[i].z; qv[4*i+3] = q[i].w;
        }
        qv[32] = q8.x; qv[33] = q8.y;
#pragma unroll
        for (int k = 0; k < NN; ++k) wv[k] = qv[k] + er[k];
        float a[12];
#pragma unroll
        for (int i = 0; i < 11; ++i) a[i] = fmax3(wv[3*i], wv[3*i+1], wv[3*i+2]);
        a[11] = wv[33];
        float b0 = fmax3(a[0], a[1], a[2]), b1 = fmax3(a[3], a[4], a[5]);
        float b2 = fmax3(a[6], a[7], a[8]), b3 = fmax3(a[9], a[10], a[11]);
        bm = fmaxf(fmaxf(b0, b1), fmaxf(b2, b3));
        int e[NN];
#pragma unroll
        for (int k = 0; k < NN; ++k) e[k] = (wv[k] == bm) ? k : 127;
        int r[12];
#pragma unroll
        for (int i = 0; i < 11; ++i) r[i] = imin3(e[3*i], e[3*i+1], e[3*i+2]);
        r[11] = e[33];
        int s0 = imin3(r[0], r[1], r[2]),  s1 = imin3(r[3], r[4], r[5]);
        int s2 = imin3(r[6], r[7], r[8]),  s3 = imin3(r[9], r[10], r[11]);
        bi = imin2(imin2(s0, s1), imin2(s2, s3));
    }
    if (lane == 0) out[bg] = bm;

    // ---- backtrack on this wave's own bp (stores by this wave; L2-resident)
    asm volatile("s_waitcnt vmcnt(0)" ::: "memory");
    const unsigned char* __restrict__ bb = bpg + (size_t)bg * TT * NN;

    // level-1: 16 chunks x 64 steps x 34 hypotheses; lane (c=lane>>2, sub),
    // 9 interleaved chases per lane (ILP hides L2 latency)
    {
        const int c = lane >> 2;
        const int sub = lane & 3;
        int mv[9];
#pragma unroll
        for (int qi = 0; qi < 9; ++qi) {
            int x = sub + 4 * qi;
            mv[qi] = (x < NN) ? x : (NN - 1);
        }
        const unsigned char* cb = bb + (size_t)c * 64 * NN;
        for (int i = 63; i >= 0; --i) {
            const unsigned char* rb = cb + (size_t)i * NN;
#pragma unroll
            for (int qi = 0; qi < 9; ++qi) mv[qi] = rb[mv[qi]];
        }
#pragma unroll
        for (int qi = 0; qi < 9; ++qi) {
            int x = sub + 4 * qi;
            if (x < NN) Fm[c][x] = (unsigned char)mv[qi];
        }
    }

    // level-2: serial 16-chunk scan (same-wave in-order DS, no barrier)
    if (lane == 0) {
        int e = bi;
        Eb[15] = e;
        for (int c = 15; c >= 1; --c) { e = Fm[c][e]; Eb[c - 1] = e; }
    }

    // emit: winning hypothesis per chunk re-chases and writes the path
    float* po = out + BB + (size_t)bg * (TT + 1);
    if (lane < 16) {
        int c = lane;
        int m = Eb[c];
        for (int i = 63; i >= 0; --i) {
            m = bb[(size_t)((c * 64 + i) * NN) + m];
            po[c * 64 + i] = (float)m;
        }
    }
    if (lane == 16) po[TT] = (float)bi;
}

extern "C" void kernel_launch(void* const* d_in, const int* in_sizes, int n_in,
                              void* d_out, int out_size, void* d_ws, size_t ws_size,
                              hipStream_t stream) {
    const float* feat  = (const float*)d_in[0];   // [1024,1024,34]
    const float* trans = (const float*)d_in[1];   // [34,34]
    float* out = (float*)d_out;                   // 1024 + 1024*1025 floats
    unsigned char* bp = (unsigned char*)d_ws;     // 35,651,584 B backpointers

    viterbi_wave<<<BB, 64, 0, stream>>>(feat, trans, bp, out);
}

// Round 5
// 622.032 us; speedup vs baseline: 1.0194x; 1.0194x over previous
//
#include <hip/hip_runtime.h>
#include <stdint.h>

// Viterbi CRF decode: B=1024, T=1024, N=34 (32 tags + START=32 + END=33)
// One wave per batch, one wave per 64-thread block (grid 1024 = 1 wave/SIMD).
// lane j = target state (j<34 active). Scores broadcast via per-block LDS.
// Forward recursion has NO barriers: same-wave DS ops are pipe-ordered.
// All forward-pass LDS ops are inline-asm volatile:
//   write m -> issue 9 broadcast reads -> (argmax eq-scan + bp store run in
//   the LDS latency shadow) -> s_waitcnt lgkmcnt(0) -> next step's adds.
// Volatile asm is mutually ordered and CANNOT be sunk by the scheduler --
// this defeats the rounds-2/3 pathology where the 8-wave register-pressure
// target made the compiler sink the LDS reads onto the critical path
// (VGPR_Count was pinned at 64 = 512/8 both rounds).
#define BB 1024
#define TT 1024
#define NN 34
#define NEGV -6969.0f

typedef float v2f __attribute__((ext_vector_type(2)));
typedef float v4f __attribute__((ext_vector_type(4)));

__device__ __forceinline__ float fmax3(float a, float b, float c) {
    return fmaxf(fmaxf(a, b), c);   // fuses to v_max3_f32
}
__device__ __forceinline__ int imin2(int a, int b) { return a < b ? a : b; }
__device__ __forceinline__ int imin3(int a, int b, int c) {
    return imin2(imin2(a, b), c);   // fuses to v_min3_i32
}

__global__ __launch_bounds__(64) void viterbi_wave(
        const float* __restrict__ feat,   // [B,T,34]
        const float* __restrict__ trans,  // [34,34]
        unsigned char* __restrict__ bpg,  // workspace [B,T,34] backpointers
        float* __restrict__ out)          // best[B] ++ path[B,T+1]
{
    __shared__ __align__(16) float scW[64];   // score broadcast (this wave)
    __shared__ unsigned char Fm[16][NN];      // backtrack level-1 results
    __shared__ int Eb[16];                    // backtrack level-2 carries

    const int lane = threadIdx.x & 63;
    const int j    = lane;                    // target state
    const int jm   = (j < NN) ? j : (NN - 1); // clamp for idle lanes
    const bool act = (j < NN);
    const int bg   = blockIdx.x;

    // ---- per-lane constants: transitions row j (34 floats, packed)
    v4f t4[8]; v2f t2;
    {
        const float* trow = trans + jm * NN;
#pragma unroll
        for (int i = 0; i < 8; ++i)
            t4[i] = (v4f){trow[4*i], trow[4*i+1], trow[4*i+2], trow[4*i+3]};
        t2 = (v2f){trow[32], trow[33]};
    }

    const float* fp = feat + (size_t)bg * TT * NN + jm;
    unsigned char* bpt = bpg + (size_t)bg * TT * NN + j;

    // LDS byte addresses (low 32 bits of the generic address = LDS offset)
    const uint32_t lbase = (uint32_t)(uintptr_t)(&scW[0]);
    const uint32_t lwr   = lbase + ((uint32_t)lane << 2);

    // broadcast score registers (asm outputs -> cannot be sunk/remat'd)
    v4f q0, q1, q2, q3, q4, q5, q6, q7; v2f q8v;

#define RD_ALL()                                                              \
    asm volatile("ds_read_b128 %0, %1 offset:0"   : "=v"(q0)  : "v"(lbase)); \
    asm volatile("ds_read_b128 %0, %1 offset:16"  : "=v"(q1)  : "v"(lbase)); \
    asm volatile("ds_read_b128 %0, %1 offset:32"  : "=v"(q2)  : "v"(lbase)); \
    asm volatile("ds_read_b128 %0, %1 offset:48"  : "=v"(q3)  : "v"(lbase)); \
    asm volatile("ds_read_b128 %0, %1 offset:64"  : "=v"(q4)  : "v"(lbase)); \
    asm volatile("ds_read_b128 %0, %1 offset:80"  : "=v"(q5)  : "v"(lbase)); \
    asm volatile("ds_read_b128 %0, %1 offset:96"  : "=v"(q6)  : "v"(lbase)); \
    asm volatile("ds_read_b128 %0, %1 offset:112" : "=v"(q7)  : "v"(lbase)); \
    asm volatile("ds_read_b64  %0, %1 offset:128" : "=v"(q8v) : "v"(lbase))

    // ---- init scores (lane k holds score[k]); lanes>=34 junk, never read
    {
        float iv = (lane == 32) ? 0.0f : NEGV;
        asm volatile("ds_write_b32 %0, %1" :: "v"(lwr), "v"(iv));
        RD_ALL();
        asm volatile("s_waitcnt lgkmcnt(0)" ::: "memory");
        __builtin_amdgcn_sched_barrier(0);
    }

    // 4-deep feature prefetch ring (t = 0..3)
    float fr0 = fp[0*NN], fr1 = fp[1*NN], fr2 = fp[2*NN], fr3 = fp[3*NN];

    // one Viterbi step. exact fp order (s+f)+tr; argmax = first index at max.
    auto vstep = [&](float fv, unsigned char* bpw) {
        const v4f f4 = (v4f){fv, fv, fv, fv};
        const v2f f2 = (v2f){fv, fv};
        v4f w0 = (q0 + f4) + t4[0];   // v_pk_add_f32 pairs
        v4f w1 = (q1 + f4) + t4[1];
        v4f w2 = (q2 + f4) + t4[2];
        v4f w3 = (q3 + f4) + t4[3];
        v4f w4 = (q4 + f4) + t4[4];
        v4f w5 = (q5 + f4) + t4[5];
        v4f w6 = (q6 + f4) + t4[6];
        v4f w7 = (q7 + f4) + t4[7];
        v2f w8 = (q8v + f2) + t2;
        float wv[NN];
#define UNP(i, W) wv[4*(i)+0]=(W).x; wv[4*(i)+1]=(W).y; \
                  wv[4*(i)+2]=(W).z; wv[4*(i)+3]=(W).w;
        UNP(0, w0) UNP(1, w1) UNP(2, w2) UNP(3, w3)
        UNP(4, w4) UNP(5, w5) UNP(6, w6) UNP(7, w7)
#undef UNP
        wv[32] = w8.x; wv[33] = w8.y;
        float a[12];
#pragma unroll
        for (int i = 0; i < 11; ++i) a[i] = fmax3(wv[3*i], wv[3*i+1], wv[3*i+2]);
        a[11] = wv[33];
        float b0 = fmax3(a[0], a[1], a[2]), b1 = fmax3(a[3], a[4], a[5]);
        float b2 = fmax3(a[6], a[7], a[8]), b3 = fmax3(a[9], a[10], a[11]);
        float m = fmaxf(fmaxf(b0, b1), fmaxf(b2, b3));
        // publish score[j], then issue refill reads (DS pipe is in-order)
        asm volatile("ds_write_b32 %0, %1" :: "v"(lwr), "v"(m));
        RD_ALL();
        // ---- LDS latency shadow: argmax eq-TREE + bp store
        int e[NN];
#pragma unroll
        for (int k = 0; k < NN; ++k) e[k] = (wv[k] == m) ? k : 127;
        int r[12];
#pragma unroll
        for (int i = 0; i < 11; ++i) r[i] = imin3(e[3*i], e[3*i+1], e[3*i+2]);
        r[11] = e[33];
        int s0 = imin3(r[0], r[1], r[2]),  s1 = imin3(r[3], r[4], r[5]);
        int s2 = imin3(r[6], r[7], r[8]),  s3 = imin3(r[9], r[10], r[11]);
        int am = imin2(imin2(s0, s1), imin2(s2, s3));
        if (act) *bpw = (unsigned char)am;
        // ---- end shadow; wait for reads, fence both ways (rule #18)
        __builtin_amdgcn_sched_barrier(0);
        asm volatile("s_waitcnt lgkmcnt(0)" ::: "memory");
        __builtin_amdgcn_sched_barrier(0);
    };

    // ---- forward: 255 iters x 4 steps (prefetch t+4) + 4-step epilogue
    for (int n = 0; n < 255; ++n) {
        { float f = fr0; fr0 = fp[4*NN]; vstep(f, bpt + 0*NN); }
        { float f = fr1; fr1 = fp[5*NN]; vstep(f, bpt + 1*NN); }
        { float f = fr2; fr2 = fp[6*NN]; vstep(f, bpt + 2*NN); }
        { float f = fr3; fr3 = fp[7*NN]; vstep(f, bpt + 3*NN); }
        fp += 4*NN; bpt += 4*NN;
    }
    vstep(fr0, bpt + 0*NN);
    vstep(fr1, bpt + 1*NN);
    vstep(fr2, bpt + 2*NN);
    vstep(fr3, bpt + 3*NN);
    // q0..q8v hold the broadcast of final scores (t=1024) in every lane.

    // ---- end transition + final argmax (redundant in all lanes, no LDS)
    int bi;
    float bm;
    {
        const float* er = trans + (NN - 1) * NN;   // uniform -> s_loads
        float qv[NN];
#define UNQ(i, W) qv[4*(i)+0]=(W).x; qv[4*(i)+1]=(W).y; \
                  qv[4*(i)+2]=(W).z; qv[4*(i)+3]=(W).w;
        UNQ(0, q0) UNQ(1, q1) UNQ(2, q2) UNQ(3, q3)
        UNQ(4, q4) UNQ(5, q5) UNQ(6, q6) UNQ(7, q7)
#undef UNQ
        qv[32] = q8v.x; qv[33] = q8v.y;
        float wv[NN];
#pragma unroll
        for (int k = 0; k < NN; ++k) wv[k] = qv[k] + er[k];
        float a[12];
#pragma unroll
        for (int i = 0; i < 11; ++i) a[i] = fmax3(wv[3*i], wv[3*i+1], wv[3*i+2]);
        a[11] = wv[33];
        float b0 = fmax3(a[0], a[1], a[2]), b1 = fmax3(a[3], a[4], a[5]);
        float b2 = fmax3(a[6], a[7], a[8]), b3 = fmax3(a[9], a[10], a[11]);
        bm = fmaxf(fmaxf(b0, b1), fmaxf(b2, b3));
        int e[NN];
#pragma unroll
        for (int k = 0; k < NN; ++k) e[k] = (wv[k] == bm) ? k : 127;
        int r[12];
#pragma unroll
        for (int i = 0; i < 11; ++i) r[i] = imin3(e[3*i], e[3*i+1], e[3*i+2]);
        r[11] = e[33];
        int s0 = imin3(r[0], r[1], r[2]),  s1 = imin3(r[3], r[4], r[5]);
        int s2 = imin3(r[6], r[7], r[8]),  s3 = imin3(r[9], r[10], r[11]);
        bi = imin2(imin2(s0, s1), imin2(s2, s3));
    }
    if (lane == 0) out[bg] = bm;

    // ---- backtrack on this wave's own bp (stores by this wave; L2-resident)
    asm volatile("s_waitcnt vmcnt(0)" ::: "memory");
    const unsigned char* __restrict__ bb = bpg + (size_t)bg * TT * NN;

    // level-1: 16 chunks x 64 steps x 34 hypotheses; lane (c=lane>>2, sub),
    // 9 interleaved chases per lane (ILP hides L2 latency)
    {
        const int c = lane >> 2;
        const int sub = lane & 3;
        int mv[9];
#pragma unroll
        for (int qi = 0; qi < 9; ++qi) {
            int x = sub + 4 * qi;
            mv[qi] = (x < NN) ? x : (NN - 1);
        }
        const unsigned char* cb = bb + (size_t)c * 64 * NN;
        for (int i = 63; i >= 0; --i) {
            const unsigned char* rb = cb + (size_t)i * NN;
#pragma unroll
            for (int qi = 0; qi < 9; ++qi) mv[qi] = rb[mv[qi]];
        }
#pragma unroll
        for (int qi = 0; qi < 9; ++qi) {
            int x = sub + 4 * qi;
            if (x < NN) Fm[c][x] = (unsigned char)mv[qi];
        }
    }

    // level-2: serial 16-chunk scan (same-wave in-order DS, no barrier)
    if (lane == 0) {
        int e = bi;
        Eb[15] = e;
        for (int c = 15; c >= 1; --c) { e = Fm[c][e]; Eb[c - 1] = e; }
    }

    // emit: winning hypothesis per chunk re-chases and writes the path
    float* po = out + BB + (size_t)bg * (TT + 1);
    if (lane < 16) {
        int c = lane;
        int m = Eb[c];
        for (int i = 63; i >= 0; --i) {
            m = bb[(size_t)((c * 64 + i) * NN) + m];
            po[c * 64 + i] = (float)m;
        }
    }
    if (lane == 16) po[TT] = (float)bi;
}

extern "C" void kernel_launch(void* const* d_in, const int* in_sizes, int n_in,
                              void* d_out, int out_size, void* d_ws, size_t ws_size,
                              hipStream_t stream) {
    const float* feat  = (const float*)d_in[0];   // [1024,1024,34]
    const float* trans = (const float*)d_in[1];   // [34,34]
    float* out = (float*)d_out;                   // 1024 + 1024*1025 floats
    unsigned char* bp = (unsigned char*)d_ws;     // 35,651,584 B backpointers

    viterbi_wave<<<BB, 64, 0, stream>>>(feat, trans, bp, out);
}